// Round 10
// baseline (388.593 us; speedup 1.0000x reference)
//
#include <hip/hip_runtime.h>

#define N_NODES 20000
#define N_EDGES 640000
#define N_MT (N_EDGES/16)   // 40000 microtiles of 16 edges

typedef short short8 __attribute__((ext_vector_type(8)));
typedef float f32x4 __attribute__((ext_vector_type(4)));

// RNE float -> bf16 bits
__device__ __forceinline__ unsigned short f2bf(float x){
  unsigned int u = __builtin_bit_cast(unsigned int, x);
  u += 0x7fffu + ((u >> 16) & 1u);
  return (unsigned short)(u >> 16);
}
__device__ __forceinline__ float bf2f(unsigned short u){
  unsigned int v = ((unsigned int)u) << 16;
  return __builtin_bit_cast(float, v);
}

// wave-synchronous LDS phase boundary
__device__ __forceinline__ void wave_lds_fence(){
  __asm__ volatile("s_waitcnt lgkmcnt(0)" ::: "memory");
}

#define HIST_BLOCKS ((N_EDGES+255)/256)    // 2500
#define YN_BLOCKS   (N_NODES/16)           // 1250 (16 nodes per block)
#define AGGZ_BLOCKS 938                    // zero 3,840,000 floats, 16/thread

// ---- fused: edge-dst histogram + y = l1 linear (bf16 out) + agg zeroing ----
__global__ void k_pre(const int* __restrict__ ei, int* __restrict__ counts,
                      const float* __restrict__ ni, const float* __restrict__ na,
                      const float* __restrict__ Wl10, const float* __restrict__ Wl11,
                      unsigned short* __restrict__ y, float4* __restrict__ aggz){
  if (blockIdx.x < HIST_BLOCKS){
    int e = blockIdx.x*256 + threadIdx.x;
    if (e < N_EDGES) atomicAdd(&counts[ei[N_EDGES + e]], 1);
    return;
  }
  if (blockIdx.x >= HIST_BLOCKS + YN_BLOCKS){
    int i = (blockIdx.x - HIST_BLOCKS - YN_BLOCKS)*256 + threadIdx.x;
    if (i < 240000){
      float4 z = {0.f,0.f,0.f,0.f};
      float4* p = aggz + (size_t)i*4;
      p[0]=z; p[1]=z; p[2]=z; p[3]=z;
    }
    return;
  }
  __shared__ float sW0[1024];     // Wl10 [32][32]
  __shared__ float sW1[256];      // Wl11 [16][16]
  __shared__ float sni[16*84];    // 16 node rows, stride 84
  __shared__ float sna[16];
  const int t = threadIdx.x;
  const int nb = (blockIdx.x - HIST_BLOCKS)*16;
  for (int i=t; i<1024; i+=256) sW0[i] = Wl10[i];
  if (t < 256) sW1[t] = Wl11[t];
  for (int i=t; i<320; i+=256){
    int n = i/20, q = i - n*20;
    *(float4*)&sni[n*84 + q*4] = *(const float4*)(ni + (size_t)(nb+n)*80 + q*4);
  }
  if (t < 16) sna[t] = na[nb + t];
  __syncthreads();
  for (int i=t; i<1280; i+=256){
    int n = i/80, k = i - n*80;
    const float* row = sni + n*84;
    float a = sna[n];
    float acc = 0.f;
    if (k < 32){
      #pragma unroll
      for (int u=0; u<32; ++u) acc += row[u]*sW0[u*32+k];
      y[(size_t)nb*80 + i] = f2bf(acc * a * 0.17677669529663687f);  // 1/sqrt(32)
    } else {
      int kk = k-32, v = kk/3, ii = kk - v*3;
      #pragma unroll
      for (int u=0; u<16; ++u) acc += row[32+u*3+ii]*sW1[u*16+v];
      y[(size_t)nb*80 + i] = f2bf(acc * a * 0.25f);                  // 1/sqrt(16)
    }
  }
}

// single-block parallel exclusive scan of counts -> cursor (proven round-2)
__global__ void k_scan(const int* __restrict__ counts, int* __restrict__ cursor){
  __shared__ int wsum[16];
  __shared__ int s_run;
  int t = threadIdx.x;            // 1024 threads
  int lane = t & 63, wv = t >> 6;
  if (t == 0) s_run = 0;
  __syncthreads();
  for (int base = 0; base < N_NODES; base += 1024){
    int i = base + t;
    int v = (i < N_NODES) ? counts[i] : 0;
    int x = v;
    #pragma unroll
    for (int off=1; off<64; off<<=1){
      int sh = __shfl_up(x, off, 64);
      if (lane >= off) x += sh;
    }
    if (lane == 63) wsum[wv] = x;
    __syncthreads();
    if (wv == 0 && lane < 16){
      int s = wsum[lane];
      #pragma unroll
      for (int off=1; off<16; off<<=1){
        int sh = __shfl_up(s, off, 64);
        if (lane >= off) s += sh;
      }
      wsum[lane] = s;
    }
    __syncthreads();
    int wbase = (wv == 0) ? 0 : wsum[wv-1];
    int run = s_run;
    if (i < N_NODES) cursor[i] = run + wbase + (x - v);
    __syncthreads();
    if (t == 0) s_run = run + wsum[15];
    __syncthreads();
  }
}

// One 64B record per edge at its sorted position:
// f[16] = {ea0..ea3, es0..es9, src, dst}
__global__ void k_fill(const int* __restrict__ ei, const float* __restrict__ ea,
                       const float* __restrict__ es, int* __restrict__ cursor,
                       float4* __restrict__ meta){
  int e = blockIdx.x*256 + threadIdx.x;
  if (e >= N_EDGES) return;
  int s = ei[e], d = ei[N_EDGES + e];
  int pos = atomicAdd(&cursor[d], 1);
  const float* eap = ea + (size_t)e*4;
  const float* esp = es + (size_t)e*10;
  float4 v0, v1, v2, v3;
  v0.x = eap[0]; v0.y = eap[1]; v0.z = eap[2]; v0.w = eap[3];
  v1.x = esp[0]; v1.y = esp[1]; v1.z = esp[2]; v1.w = esp[3];
  v2.x = esp[4]; v2.y = esp[5]; v2.z = esp[6]; v2.w = esp[7];
  v3.x = esp[8]; v3.y = esp[9];
  v3.z = __int_as_float(s); v3.w = __int_as_float(d);
  float4* mp = meta + (size_t)pos*4;
  mp[0] = v0; mp[1] = v1; mp[2] = v2; mp[3] = v3;
}

// ---------------- fused edge MLP + messages + segment-sum ----------------
// bf16 y + bf16 w in LDS => 31.5 KB/block => 5 blocks/CU by LDS.
// launch_bounds caps at 4 waves/SIMD (VGPR<=128): compiler's natural ~84
// VGPRs stays spill-free (round 9's (256,5) forced VGPR=48 => scratch
// spills, +140MB HBM traffic, zero net gain).
__global__ __launch_bounds__(256, 4) void k_edge(
    const float4* __restrict__ meta,
    const float* __restrict__ Wfc0, const float* __restrict__ Wfc1,
    const unsigned short* __restrict__ yb, float* __restrict__ agg){
  __shared__ float s_wfc0[640];                    // [k=10][n=64] f32
  __shared__ unsigned short s_w[4][16*98];         // per-wave: [e=16][o=96(+2)] bf16
  __shared__ unsigned short s_y[4][16*88];         // per-wave: y rows bf16, stride 88
  __shared__ float s_m[4][16*20];                  // per-wave: ea[0..3], es[4..13], src/dst[14..15]

  const int t = threadIdx.x;
  const int w = t >> 6, l = t & 63;
  const int r = l & 15, part = l >> 4;

  for (int i = t; i < 640; i += 256) s_wfc0[i] = Wfc0[i];

  // B-fragments of Wfc1 (bf16) in registers: lane holds B[k=part*8+j][n=nt*16+r]
  short8 b0[6], b1[6];
  #pragma unroll
  for (int nt=0; nt<6; ++nt){
    #pragma unroll
    for (int j=0; j<8; ++j){
      b0[nt][j] = (short)f2bf(Wfc1[(     part*8+j)*96 + nt*16 + r]);
      b1[nt][j] = (short)f2bf(Wfc1[(32 + part*8+j)*96 + nt*16 + r]);
    }
  }
  __syncthreads();   // only block barrier: s_wfc0 ready

  // per-lane message-channel constants (3 channel passes, c = p*64 + l)
  int o_c[3], yo[3], eai[3];
  #pragma unroll
  for (int p=0; p<3; ++p){
    int c = p*64 + l;
    if (c < 32)      { o_c[p]=c;    yo[p]=c;        eai[p]=0; }
    else if (c < 48) { int u=c-32;  o_c[p]=80+u;    yo[p]=32+3*u; eai[p]=0; }
    else if (c < 144){ int idx=c-48;  int u=idx/3, fi=idx-u*3; o_c[p]=32+u; yo[p]=u;        eai[p]=1+fi; }
    else             { int idx=c-144; int u=idx/3, i =idx-u*3; o_c[p]=64+u; yo[p]=32+3*u+i; eai[p]=0; }
  }
  const bool dot0 = (l >= 32) && (l < 48);

  unsigned short* sw = s_w[w];
  unsigned short* sy = s_y[w];
  float* sm = s_m[w];

  // y-row chunk assignment (16B chunks of the 160B bf16 row)
  const int o0 = (part==0) ? 0 : (part==1) ? 24 : (part==2) ? 40 : 64;
  const bool has3 = (part & 1) == 0;

  const int gw = blockIdx.x*4 + w;
  const int nw = gridDim.x*4;
  const int m0 = (int)(((long long)gw     * N_MT) / nw);
  const int m1 = (int)(((long long)(gw+1) * N_MT) / nw);
  if (m0 >= m1) return;

  // ---- prologue: tile m0 meta
  float4 mreg = meta[(size_t)m0*64 + l];

  float acc0 = 0.f, acc1 = 0.f, acc2 = 0.f;
  int dcur = -1;

  for (int m = m0; m < m1; ++m){
    // ---- next-tile meta prefetch (clamped; only 4 VGPRs cross phases)
    const int mnx = (m+1 < m1) ? (m+1) : m;
    float4 mnext = meta[(size_t)mnx*64 + l];

    // ---- extract src/dst for this tile from mreg
    const int isrc = __float_as_int(__shfl(mreg.z, 4*r + 3));
    const int idst = __float_as_int(__shfl(mreg.w, 4*r + 3));

    // ---- current-tile y gather, bf16 (global->reg->LDS, short live range)
    {
      const unsigned short* yrow = yb + (size_t)isrc*80;
      uint4 va = *(const uint4*)(yrow + o0);
      uint4 vb = *(const uint4*)(yrow + o0 + 8);
      uint4 vc;
      if (has3) vc = *(const uint4*)(yrow + o0 + 16);
      unsigned short* syr = sy + r*88;
      *(uint4*)(syr + o0)      = va;
      *(uint4*)(syr + o0 + 8)  = vb;
      if (has3) *(uint4*)(syr + o0 + 16) = vc;
    }
    *(float4*)(sm + (l>>2)*20 + (l&3)*4) = mreg;
    wave_lds_fence();

    // ---- layer1: h[r][part*8+j] from s_m es
    const float* esr = sm + r*20 + 4;
    float hv0[8], hv1[8];
    #pragma unroll
    for (int j=0; j<8; ++j){ hv0[j]=0.f; hv1[j]=0.f; }
    #pragma unroll
    for (int k=0; k<10; ++k){
      float ev = esr[k];
      const float* wr = s_wfc0 + k*64 + part*8;
      #pragma unroll
      for (int j=0; j<8; ++j){ hv0[j] += ev*wr[j]; hv1[j] += ev*wr[32+j]; }
    }
    short8 a0, a1;
    #pragma unroll
    for (int j=0; j<8; ++j){
      float x0 = hv0[j]*0.31622776601683794f;   // /sqrt(10)
      float x1 = hv1[j]*0.31622776601683794f;
      a0[j] = (short)f2bf(x0/(1.f+__expf(-x0)));
      a1[j] = (short)f2bf(x1/(1.f+__expf(-x1)));
    }

    // ---- layer2 MFMA: w[e=part*4+rr][o=nt*16+r] -> bf16 LDS
    #pragma unroll
    for (int nt=0; nt<6; ++nt){
      f32x4 acc = {0.f,0.f,0.f,0.f};
      acc = __builtin_amdgcn_mfma_f32_16x16x32_bf16(a0, b0[nt], acc, 0,0,0);
      acc = __builtin_amdgcn_mfma_f32_16x16x32_bf16(a1, b1[nt], acc, 0,0,0);
      #pragma unroll
      for (int rr=0; rr<4; ++rr)
        sw[(part*4+rr)*98 + nt*16 + r] = f2bf(acc[rr]*0.125f);   // /sqrt(64)
    }
    wave_lds_fence();

    // ---- messages + carried segment-sum (3 channels per lane)
    for (int e=0; e<16; ++e){
      int de = __shfl(idst, e);
      if (de != dcur){
        if (dcur >= 0){
          unsafeAtomicAdd(&agg[(size_t)dcur*192 +       l], acc0);
          unsafeAtomicAdd(&agg[(size_t)dcur*192 +  64 + l], acc1);
          unsafeAtomicAdd(&agg[(size_t)dcur*192 + 128 + l], acc2);
        }
        acc0 = acc1 = acc2 = 0.f;
        dcur = de;
      }
      const float* sme = sm + e*20;
      const unsigned short* swe = sw + e*98;
      const unsigned short* sye = sy + e*88;
      float m0v;
      if (dot0){
        m0v = bf2f(swe[o_c[0]]) *
              (bf2f(sye[yo[0]])*sme[1] + bf2f(sye[yo[0]+1])*sme[2] + bf2f(sye[yo[0]+2])*sme[3])
              * 0.5773502691896258f;   // /sqrt(3)
      } else {
        m0v = bf2f(swe[o_c[0]]) * bf2f(sye[yo[0]]) * sme[eai[0]];
      }
      acc0 += m0v;
      acc1 += bf2f(swe[o_c[1]]) * bf2f(sye[yo[1]]) * sme[eai[1]];
      acc2 += bf2f(swe[o_c[2]]) * bf2f(sye[yo[2]]) * sme[eai[2]];
    }
    wave_lds_fence();

    mreg = mnext;
  }
  if (dcur >= 0){
    unsafeAtomicAdd(&agg[(size_t)dcur*192 +       l], acc0);
    unsafeAtomicAdd(&agg[(size_t)dcur*192 +  64 + l], acc1);
    unsafeAtomicAdd(&agg[(size_t)dcur*192 + 128 + l], acc2);
  }
}

// ---------------- finish: z = agg @ W_l2, out = c_s*s + c_x*z ----------------
__global__ void k_finish(const float* __restrict__ ni, const float* __restrict__ na,
    const float* __restrict__ Wsc0, const float* __restrict__ Wsc1,
    const float* __restrict__ Wl20, const float* __restrict__ Wl21,
    const float* __restrict__ agg, float* __restrict__ out){
  __shared__ float sWsc0[1024];   // [32][32]
  __shared__ float sWsc1[256];    // [16][16]
  __shared__ float sWl20[1536];   // [48][32]
  __shared__ float sWl21[768];    // [48][16]
  __shared__ float sni[16*84];    // node rows, stride 84
  __shared__ float sag[16*196];   // agg rows, stride 196
  __shared__ float sna[16];
  const int t = threadIdx.x;
  const int nb = blockIdx.x*16;
  for (int i=t; i<1024; i+=256) sWsc0[i] = Wsc0[i];
  if (t < 256) sWsc1[t] = Wsc1[t];
  for (int i=t; i<1536; i+=256) sWl20[i] = Wl20[i];
  for (int i=t; i<768;  i+=256) sWl21[i] = Wl21[i];
  for (int i=t; i<320;  i+=256){
    int n = i/20, q = i - n*20;
    *(float4*)&sni[n*84 + q*4] = *(const float4*)(ni + (size_t)(nb+n)*80 + q*4);
  }
  for (int i=t; i<768;  i+=256){
    int n = i/48, q = i - n*48;
    *(float4*)&sag[n*196 + q*4] = *(const float4*)(agg + (size_t)(nb+n)*192 + q*4);
  }
  if (t < 16) sna[t] = na[nb + t];
  __syncthreads();

  const float c_s = 0.3826834323650898f;   // sin(pi/8)
  const float c_x = 0.9238795325112867f;   // cos(pi/8)
  const float zscale = 0.17677669529663687f * 0.14433756729740643f; // 1/sqrt(32)/sqrt(48)
  for (int i=t; i<1280; i+=256){
    int n = i/80, k = i - n*80;
    const float* row = sni + n*84;
    const float* ag  = sag + n*196;
    float a = sna[n];
    float s = 0.f, z = 0.f;
    if (k < 32){
      #pragma unroll
      for (int u=0; u<32; ++u) s += row[u]*sWsc0[u*32+k];
      s *= a * 0.17677669529663687f;
      #pragma unroll
      for (int u=0; u<48; ++u) z += ag[u]*sWl20[u*32+k];
    } else {
      int kk=k-32, v=kk/3, ii=kk-v*3;
      #pragma unroll
      for (int u=0; u<16; ++u) s += row[32+u*3+ii]*sWsc1[u*16+v];
      s *= a * 0.25f;
      #pragma unroll
      for (int u=0; u<48; ++u) z += ag[48+u*3+ii]*sWl21[u*16+v];
    }
    out[(size_t)nb*80 + i] = c_s*s + c_x*z*zscale;
  }
}

extern "C" void kernel_launch(void* const* d_in, const int* in_sizes, int n_in,
                              void* d_out, int out_size, void* d_ws, size_t ws_size,
                              hipStream_t stream){
  const float* node_input   = (const float*)d_in[0];
  const float* node_attr    = (const float*)d_in[1];
  const float* edge_attr    = (const float*)d_in[2];
  const float* edge_scalars = (const float*)d_in[3];
  const float* W_sc0 = (const float*)d_in[4];
  const float* W_sc1 = (const float*)d_in[5];
  const float* W_l1_0 = (const float*)d_in[6];
  const float* W_l1_1 = (const float*)d_in[7];
  const float* W_fc0 = (const float*)d_in[8];
  const float* W_fc1 = (const float*)d_in[9];
  const float* W_l2_0 = (const float*)d_in[10];
  const float* W_l2_1 = (const float*)d_in[11];
  const int* edge_index = (const int*)d_in[12];
  float* out = (float*)d_out;

  char* ws = (char*)d_ws;
  unsigned short* y = (unsigned short*)ws;            //  3,200,000 B (bf16)
  float*  agg    = (float*)(ws + 3200000);            // 15,360,000 B
  int*    counts = (int*)(ws + 18560000);             // 80,000 B
  int*    cursor = (int*)(ws + 18640064);             // 80,000 B
  float4* meta   = (float4*)(ws + 18722048);          // 40,960,000 B (64-aligned)

  // zero counts only (agg zeroed inside k_pre)
  hipMemsetAsync(counts, 0, 80000, stream);

  k_pre  <<<HIST_BLOCKS + YN_BLOCKS + AGGZ_BLOCKS, 256, 0, stream>>>(
            edge_index, counts, node_input, node_attr, W_l1_0, W_l1_1,
            y, (float4*)agg);
  k_scan <<<1, 1024, 0, stream>>>(counts, cursor);
  k_fill <<<(N_EDGES+255)/256, 256, 0, stream>>>(edge_index, edge_attr, edge_scalars,
                                                 cursor, meta);
  k_edge <<<1280, 256, 0, stream>>>(meta, W_fc0, W_fc1, y, agg);
  k_finish<<<YN_BLOCKS, 256, 0, stream>>>(node_input, node_attr, W_sc0, W_sc1,
                                          W_l2_0, W_l2_1, agg, out);
}

// Round 11
// 349.486 us; speedup vs baseline: 1.1119x; 1.1119x over previous
//
#include <hip/hip_runtime.h>

#define N_NODES 20000
#define N_EDGES 640000
#define N_MT (N_EDGES/16)   // 40000 microtiles of 16 edges

typedef short short8 __attribute__((ext_vector_type(8)));
typedef float f32x4 __attribute__((ext_vector_type(4)));

// RNE float -> bf16 bits
__device__ __forceinline__ unsigned short f2bf(float x){
  unsigned int u = __builtin_bit_cast(unsigned int, x);
  u += 0x7fffu + ((u >> 16) & 1u);
  return (unsigned short)(u >> 16);
}
__device__ __forceinline__ float bf2f(unsigned short u){
  unsigned int v = ((unsigned int)u) << 16;
  return __builtin_bit_cast(float, v);
}

// wave-synchronous LDS phase boundary
__device__ __forceinline__ void wave_lds_fence(){
  __asm__ volatile("s_waitcnt lgkmcnt(0)" ::: "memory");
}

#define HIST_BLOCKS ((N_EDGES+255)/256)    // 2500
#define YN_BLOCKS   (N_NODES/16)           // 1250 (16 nodes per block)
#define AGGZ_BLOCKS 938                    // zero 3,840,000 floats, 16/thread

// ---- fused: edge-dst histogram + y = l1 linear (bf16 out) + agg zeroing ----
__global__ void k_pre(const int* __restrict__ ei, int* __restrict__ counts,
                      const float* __restrict__ ni, const float* __restrict__ na,
                      const float* __restrict__ Wl10, const float* __restrict__ Wl11,
                      unsigned short* __restrict__ y, float4* __restrict__ aggz){
  if (blockIdx.x < HIST_BLOCKS){
    int e = blockIdx.x*256 + threadIdx.x;
    if (e < N_EDGES) atomicAdd(&counts[ei[N_EDGES + e]], 1);
    return;
  }
  if (blockIdx.x >= HIST_BLOCKS + YN_BLOCKS){
    int i = (blockIdx.x - HIST_BLOCKS - YN_BLOCKS)*256 + threadIdx.x;
    if (i < 240000){
      float4 z = {0.f,0.f,0.f,0.f};
      float4* p = aggz + (size_t)i*4;
      p[0]=z; p[1]=z; p[2]=z; p[3]=z;
    }
    return;
  }
  __shared__ float sW0[1024];     // Wl10 [32][32]
  __shared__ float sW1[256];      // Wl11 [16][16]
  __shared__ float sni[16*84];    // 16 node rows, stride 84
  __shared__ float sna[16];
  const int t = threadIdx.x;
  const int nb = (blockIdx.x - HIST_BLOCKS)*16;
  for (int i=t; i<1024; i+=256) sW0[i] = Wl10[i];
  if (t < 256) sW1[t] = Wl11[t];
  for (int i=t; i<320; i+=256){
    int n = i/20, q = i - n*20;
    *(float4*)&sni[n*84 + q*4] = *(const float4*)(ni + (size_t)(nb+n)*80 + q*4);
  }
  if (t < 16) sna[t] = na[nb + t];
  __syncthreads();
  for (int i=t; i<1280; i+=256){
    int n = i/80, k = i - n*80;
    const float* row = sni + n*84;
    float a = sna[n];
    float acc = 0.f;
    if (k < 32){
      #pragma unroll
      for (int u=0; u<32; ++u) acc += row[u]*sW0[u*32+k];
      y[(size_t)nb*80 + i] = f2bf(acc * a * 0.17677669529663687f);  // 1/sqrt(32)
    } else {
      int kk = k-32, v = kk/3, ii = kk - v*3;
      #pragma unroll
      for (int u=0; u<16; ++u) acc += row[32+u*3+ii]*sW1[u*16+v];
      y[(size_t)nb*80 + i] = f2bf(acc * a * 0.25f);                  // 1/sqrt(16)
    }
  }
}

// block-level base allocation: per-block prefix scan of 256 counts + ONE
// atomicAdd for the block's base window (order arbitrary, segments contiguous)
__global__ void k_alloc(const int* __restrict__ counts, int* __restrict__ ctr,
                        int* __restrict__ cursor){
  __shared__ int wsum[4];
  __shared__ int s_base;
  const int t = threadIdx.x;
  const int lane = t & 63, wv = t >> 6;
  const int n = blockIdx.x*256 + t;
  int v = (n < N_NODES) ? counts[n] : 0;
  int x = v;
  #pragma unroll
  for (int off=1; off<64; off<<=1){
    int sh = __shfl_up(x, off, 64);
    if (lane >= off) x += sh;
  }
  if (lane == 63) wsum[wv] = x;
  __syncthreads();
  if (t == 0){
    int s0 = wsum[0], s1 = wsum[1], s2 = wsum[2], s3 = wsum[3];
    int total = s0 + s1 + s2 + s3;
    wsum[0] = 0; wsum[1] = s0; wsum[2] = s0+s1; wsum[3] = s0+s1+s2;
    s_base = atomicAdd(ctr, total);
  }
  __syncthreads();
  if (n < N_NODES) cursor[n] = s_base + wsum[wv] + (x - v);
}

// One 64B record per edge at its sorted position:
// f[16] = {ea0..ea3, es0..es9, src, dst}
__global__ void k_fill(const int* __restrict__ ei, const float* __restrict__ ea,
                       const float* __restrict__ es, int* __restrict__ cursor,
                       float4* __restrict__ meta){
  int e = blockIdx.x*256 + threadIdx.x;
  if (e >= N_EDGES) return;
  int s = ei[e], d = ei[N_EDGES + e];
  int pos = atomicAdd(&cursor[d], 1);
  const float* eap = ea + (size_t)e*4;
  const float* esp = es + (size_t)e*10;
  float4 v0, v1, v2, v3;
  v0.x = eap[0]; v0.y = eap[1]; v0.z = eap[2]; v0.w = eap[3];
  v1.x = esp[0]; v1.y = esp[1]; v1.z = esp[2]; v1.w = esp[3];
  v2.x = esp[4]; v2.y = esp[5]; v2.z = esp[6]; v2.w = esp[7];
  v3.x = esp[8]; v3.y = esp[9];
  v3.z = __int_as_float(s); v3.w = __int_as_float(d);
  float4* mp = meta + (size_t)pos*4;
  mp[0] = v0; mp[1] = v1; mp[2] = v2; mp[3] = v3;
}

// ---------------- fused edge MLP + messages + segment-sum ----------------
// bf16 y + bf16 w in LDS => 31.5 KB/block => 5 blocks/CU by LDS.
// NO waves-per-EU hint: any 2nd launch_bounds arg makes the backend squeeze
// VGPRs to the top of the range and spill (r9: VGPR48 +140MB, r10: VGPR64
// +70MB scratch traffic). Natural allocation (~84) fits 5 blocks/CU anyway.
__global__ __launch_bounds__(256) void k_edge(
    const float4* __restrict__ meta,
    const float* __restrict__ Wfc0, const float* __restrict__ Wfc1,
    const unsigned short* __restrict__ yb, float* __restrict__ agg){
  __shared__ float s_wfc0[640];                    // [k=10][n=64] f32
  __shared__ unsigned short s_w[4][16*98];         // per-wave: [e=16][o=96(+2)] bf16
  __shared__ unsigned short s_y[4][16*88];         // per-wave: y rows bf16, stride 88
  __shared__ float s_m[4][16*20];                  // per-wave: ea[0..3], es[4..13], src/dst[14..15]

  const int t = threadIdx.x;
  const int w = t >> 6, l = t & 63;
  const int r = l & 15, part = l >> 4;

  for (int i = t; i < 640; i += 256) s_wfc0[i] = Wfc0[i];

  // B-fragments of Wfc1 (bf16) in registers: lane holds B[k=part*8+j][n=nt*16+r]
  short8 b0[6], b1[6];
  #pragma unroll
  for (int nt=0; nt<6; ++nt){
    #pragma unroll
    for (int j=0; j<8; ++j){
      b0[nt][j] = (short)f2bf(Wfc1[(     part*8+j)*96 + nt*16 + r]);
      b1[nt][j] = (short)f2bf(Wfc1[(32 + part*8+j)*96 + nt*16 + r]);
    }
  }
  __syncthreads();   // only block barrier: s_wfc0 ready

  // per-lane message-channel constants (3 channel passes, c = p*64 + l)
  int o_c[3], yo[3], eai[3];
  #pragma unroll
  for (int p=0; p<3; ++p){
    int c = p*64 + l;
    if (c < 32)      { o_c[p]=c;    yo[p]=c;        eai[p]=0; }
    else if (c < 48) { int u=c-32;  o_c[p]=80+u;    yo[p]=32+3*u; eai[p]=0; }
    else if (c < 144){ int idx=c-48;  int u=idx/3, fi=idx-u*3; o_c[p]=32+u; yo[p]=u;        eai[p]=1+fi; }
    else             { int idx=c-144; int u=idx/3, i =idx-u*3; o_c[p]=64+u; yo[p]=32+3*u+i; eai[p]=0; }
  }
  const bool dot0 = (l >= 32) && (l < 48);

  unsigned short* sw = s_w[w];
  unsigned short* sy = s_y[w];
  float* sm = s_m[w];

  // y-row chunk assignment (16B chunks of the 160B bf16 row)
  const int o0 = (part==0) ? 0 : (part==1) ? 24 : (part==2) ? 40 : 64;
  const bool has3 = (part & 1) == 0;

  const int gw = blockIdx.x*4 + w;
  const int nw = gridDim.x*4;
  const int m0 = (int)(((long long)gw     * N_MT) / nw);
  const int m1 = (int)(((long long)(gw+1) * N_MT) / nw);
  if (m0 >= m1) return;

  // ---- prologue: tile m0 meta
  float4 mreg = meta[(size_t)m0*64 + l];

  float acc0 = 0.f, acc1 = 0.f, acc2 = 0.f;
  int dcur = -1;

  for (int m = m0; m < m1; ++m){
    // ---- next-tile meta prefetch (clamped; only 4 VGPRs cross phases)
    const int mnx = (m+1 < m1) ? (m+1) : m;
    float4 mnext = meta[(size_t)mnx*64 + l];

    // ---- extract src/dst for this tile from mreg
    const int isrc = __float_as_int(__shfl(mreg.z, 4*r + 3));
    const int idst = __float_as_int(__shfl(mreg.w, 4*r + 3));

    // ---- current-tile y gather, bf16 (global->reg->LDS, short live range)
    {
      const unsigned short* yrow = yb + (size_t)isrc*80;
      uint4 va = *(const uint4*)(yrow + o0);
      uint4 vb = *(const uint4*)(yrow + o0 + 8);
      uint4 vc;
      if (has3) vc = *(const uint4*)(yrow + o0 + 16);
      unsigned short* syr = sy + r*88;
      *(uint4*)(syr + o0)      = va;
      *(uint4*)(syr + o0 + 8)  = vb;
      if (has3) *(uint4*)(syr + o0 + 16) = vc;
    }
    *(float4*)(sm + (l>>2)*20 + (l&3)*4) = mreg;
    wave_lds_fence();

    // ---- layer1: h[r][part*8+j] from s_m es
    const float* esr = sm + r*20 + 4;
    float hv0[8], hv1[8];
    #pragma unroll
    for (int j=0; j<8; ++j){ hv0[j]=0.f; hv1[j]=0.f; }
    #pragma unroll
    for (int k=0; k<10; ++k){
      float ev = esr[k];
      const float* wr = s_wfc0 + k*64 + part*8;
      #pragma unroll
      for (int j=0; j<8; ++j){ hv0[j] += ev*wr[j]; hv1[j] += ev*wr[32+j]; }
    }
    short8 a0, a1;
    #pragma unroll
    for (int j=0; j<8; ++j){
      float x0 = hv0[j]*0.31622776601683794f;   // /sqrt(10)
      float x1 = hv1[j]*0.31622776601683794f;
      a0[j] = (short)f2bf(x0/(1.f+__expf(-x0)));
      a1[j] = (short)f2bf(x1/(1.f+__expf(-x1)));
    }

    // ---- layer2 MFMA: w[e=part*4+rr][o=nt*16+r] -> bf16 LDS
    #pragma unroll
    for (int nt=0; nt<6; ++nt){
      f32x4 acc = {0.f,0.f,0.f,0.f};
      acc = __builtin_amdgcn_mfma_f32_16x16x32_bf16(a0, b0[nt], acc, 0,0,0);
      acc = __builtin_amdgcn_mfma_f32_16x16x32_bf16(a1, b1[nt], acc, 0,0,0);
      #pragma unroll
      for (int rr=0; rr<4; ++rr)
        sw[(part*4+rr)*98 + nt*16 + r] = f2bf(acc[rr]*0.125f);   // /sqrt(64)
    }
    wave_lds_fence();

    // ---- messages + carried segment-sum (3 channels per lane)
    for (int e=0; e<16; ++e){
      int de = __shfl(idst, e);
      if (de != dcur){
        if (dcur >= 0){
          unsafeAtomicAdd(&agg[(size_t)dcur*192 +       l], acc0);
          unsafeAtomicAdd(&agg[(size_t)dcur*192 +  64 + l], acc1);
          unsafeAtomicAdd(&agg[(size_t)dcur*192 + 128 + l], acc2);
        }
        acc0 = acc1 = acc2 = 0.f;
        dcur = de;
      }
      const float* sme = sm + e*20;
      const unsigned short* swe = sw + e*98;
      const unsigned short* sye = sy + e*88;
      float m0v;
      if (dot0){
        m0v = bf2f(swe[o_c[0]]) *
              (bf2f(sye[yo[0]])*sme[1] + bf2f(sye[yo[0]+1])*sme[2] + bf2f(sye[yo[0]+2])*sme[3])
              * 0.5773502691896258f;   // /sqrt(3)
      } else {
        m0v = bf2f(swe[o_c[0]]) * bf2f(sye[yo[0]]) * sme[eai[0]];
      }
      acc0 += m0v;
      acc1 += bf2f(swe[o_c[1]]) * bf2f(sye[yo[1]]) * sme[eai[1]];
      acc2 += bf2f(swe[o_c[2]]) * bf2f(sye[yo[2]]) * sme[eai[2]];
    }
    wave_lds_fence();

    mreg = mnext;
  }
  if (dcur >= 0){
    unsafeAtomicAdd(&agg[(size_t)dcur*192 +       l], acc0);
    unsafeAtomicAdd(&agg[(size_t)dcur*192 +  64 + l], acc1);
    unsafeAtomicAdd(&agg[(size_t)dcur*192 + 128 + l], acc2);
  }
}

// ---------------- finish: z = agg @ W_l2, out = c_s*s + c_x*z ----------------
__global__ void k_finish(const float* __restrict__ ni, const float* __restrict__ na,
    const float* __restrict__ Wsc0, const float* __restrict__ Wsc1,
    const float* __restrict__ Wl20, const float* __restrict__ Wl21,
    const float* __restrict__ agg, float* __restrict__ out){
  __shared__ float sWsc0[1024];   // [32][32]
  __shared__ float sWsc1[256];    // [16][16]
  __shared__ float sWl20[1536];   // [48][32]
  __shared__ float sWl21[768];    // [48][16]
  __shared__ float sni[16*84];    // node rows, stride 84
  __shared__ float sag[16*196];   // agg rows, stride 196
  __shared__ float sna[16];
  const int t = threadIdx.x;
  const int nb = blockIdx.x*16;
  for (int i=t; i<1024; i+=256) sWsc0[i] = Wsc0[i];
  if (t < 256) sWsc1[t] = Wsc1[t];
  for (int i=t; i<1536; i+=256) sWl20[i] = Wl20[i];
  for (int i=t; i<768;  i+=256) sWl21[i] = Wl21[i];
  for (int i=t; i<320;  i+=256){
    int n = i/20, q = i - n*20;
    *(float4*)&sni[n*84 + q*4] = *(const float4*)(ni + (size_t)(nb+n)*80 + q*4);
  }
  for (int i=t; i<768;  i+=256){
    int n = i/48, q = i - n*48;
    *(float4*)&sag[n*196 + q*4] = *(const float4*)(agg + (size_t)(nb+n)*192 + q*4);
  }
  if (t < 16) sna[t] = na[nb + t];
  __syncthreads();

  const float c_s = 0.3826834323650898f;   // sin(pi/8)
  const float c_x = 0.9238795325112867f;   // cos(pi/8)
  const float zscale = 0.17677669529663687f * 0.14433756729740643f; // 1/sqrt(32)/sqrt(48)
  for (int i=t; i<1280; i+=256){
    int n = i/80, k = i - n*80;
    const float* row = sni + n*84;
    const float* ag  = sag + n*196;
    float a = sna[n];
    float s = 0.f, z = 0.f;
    if (k < 32){
      #pragma unroll
      for (int u=0; u<32; ++u) s += row[u]*sWsc0[u*32+k];
      s *= a * 0.17677669529663687f;
      #pragma unroll
      for (int u=0; u<48; ++u) z += ag[u]*sWl20[u*32+k];
    } else {
      int kk=k-32, v=kk/3, ii=kk-v*3;
      #pragma unroll
      for (int u=0; u<16; ++u) s += row[32+u*3+ii]*sWsc1[u*16+v];
      s *= a * 0.25f;
      #pragma unroll
      for (int u=0; u<48; ++u) z += ag[48+u*3+ii]*sWl21[u*16+v];
    }
    out[(size_t)nb*80 + i] = c_s*s + c_x*z*zscale;
  }
}

extern "C" void kernel_launch(void* const* d_in, const int* in_sizes, int n_in,
                              void* d_out, int out_size, void* d_ws, size_t ws_size,
                              hipStream_t stream){
  const float* node_input   = (const float*)d_in[0];
  const float* node_attr    = (const float*)d_in[1];
  const float* edge_attr    = (const float*)d_in[2];
  const float* edge_scalars = (const float*)d_in[3];
  const float* W_sc0 = (const float*)d_in[4];
  const float* W_sc1 = (const float*)d_in[5];
  const float* W_l1_0 = (const float*)d_in[6];
  const float* W_l1_1 = (const float*)d_in[7];
  const float* W_fc0 = (const float*)d_in[8];
  const float* W_fc1 = (const float*)d_in[9];
  const float* W_l2_0 = (const float*)d_in[10];
  const float* W_l2_1 = (const float*)d_in[11];
  const int* edge_index = (const int*)d_in[12];
  float* out = (float*)d_out;

  char* ws = (char*)d_ws;
  unsigned short* y = (unsigned short*)ws;            //  3,200,000 B (bf16)
  float*  agg    = (float*)(ws + 3200000);            // 15,360,000 B
  int*    counts = (int*)(ws + 18560000);             // 80,000 B
  int*    ctr    = (int*)(ws + 18640000);             // 64 B
  int*    cursor = (int*)(ws + 18640064);             // 80,000 B
  float4* meta   = (float4*)(ws + 18722048);          // 40,960,000 B (64-aligned)

  // zero counts + ctr (agg zeroed inside k_pre)
  hipMemsetAsync(counts, 0, 80064, stream);

  k_pre  <<<HIST_BLOCKS + YN_BLOCKS + AGGZ_BLOCKS, 256, 0, stream>>>(
            edge_index, counts, node_input, node_attr, W_l1_0, W_l1_1,
            y, (float4*)agg);
  k_alloc<<<(N_NODES+255)/256, 256, 0, stream>>>(counts, ctr, cursor);
  k_fill <<<(N_EDGES+255)/256, 256, 0, stream>>>(edge_index, edge_attr, edge_scalars,
                                                 cursor, meta);
  k_edge <<<1280, 256, 0, stream>>>(meta, W_fc0, W_fc1, y, agg);
  k_finish<<<YN_BLOCKS, 256, 0, stream>>>(node_input, node_attr, W_sc0, W_sc1,
                                          W_l2_0, W_l2_1, agg, out);
}

// Round 12
// 337.359 us; speedup vs baseline: 1.1519x; 1.0359x over previous
//
#include <hip/hip_runtime.h>

#define N_NODES 20000
#define N_EDGES 640000
#define N_MT (N_EDGES/16)   // 40000 microtiles of 16 edges

typedef short short8 __attribute__((ext_vector_type(8)));
typedef float f32x4 __attribute__((ext_vector_type(4)));

// RNE float -> bf16 bits
__device__ __forceinline__ unsigned int f2bf(float x){
  unsigned int u = __builtin_bit_cast(unsigned int, x);
  u += 0x7fffu + ((u >> 16) & 1u);
  return u >> 16;
}
__device__ __forceinline__ float bf2f(unsigned short u){
  unsigned int v = ((unsigned int)u) << 16;
  return __builtin_bit_cast(float, v);
}
// low/high bf16 of a u32 -> f32 (1 VALU each)
__device__ __forceinline__ float bflo(unsigned int u){
  return __builtin_bit_cast(float, u << 16);
}
__device__ __forceinline__ float bfhi(unsigned int u){
  return __builtin_bit_cast(float, u & 0xffff0000u);
}

// wave-synchronous LDS phase boundary
__device__ __forceinline__ void wave_lds_fence(){
  __asm__ volatile("s_waitcnt lgkmcnt(0)" ::: "memory");
}

#define HIST_BLOCKS 625                    // 4 edges/thread, int4 loads
#define YN_BLOCKS   (N_NODES/16)           // 1250 (16 nodes per block)
#define AGGZ_BLOCKS 938                    // zero 3,840,000 floats, 16/thread

// ---- fused: edge-dst histogram + y = l1 linear (bf16 out) + agg zeroing ----
__global__ void k_pre(const int* __restrict__ ei, int* __restrict__ counts,
                      const float* __restrict__ ni, const float* __restrict__ na,
                      const float* __restrict__ Wl10, const float* __restrict__ Wl11,
                      unsigned short* __restrict__ y, float4* __restrict__ aggz){
  if (blockIdx.x < HIST_BLOCKS){
    int i = blockIdx.x*256 + threadIdx.x;   // i-th group of 4 dsts
    if (i < N_EDGES/4){
      int4 d4 = *(const int4*)(ei + N_EDGES + i*4);
      atomicAdd(&counts[d4.x], 1);
      atomicAdd(&counts[d4.y], 1);
      atomicAdd(&counts[d4.z], 1);
      atomicAdd(&counts[d4.w], 1);
    }
    return;
  }
  if (blockIdx.x >= HIST_BLOCKS + YN_BLOCKS){
    int i = (blockIdx.x - HIST_BLOCKS - YN_BLOCKS)*256 + threadIdx.x;
    if (i < 240000){
      float4 z = {0.f,0.f,0.f,0.f};
      float4* p = aggz + (size_t)i*4;
      p[0]=z; p[1]=z; p[2]=z; p[3]=z;
    }
    return;
  }
  __shared__ float sW0[1024];     // Wl10 [32][32]
  __shared__ float sW1[256];      // Wl11 [16][16]
  __shared__ float sni[16*84];    // 16 node rows, stride 84
  __shared__ float sna[16];
  const int t = threadIdx.x;
  const int nb = (blockIdx.x - HIST_BLOCKS)*16;
  for (int i=t; i<1024; i+=256) sW0[i] = Wl10[i];
  if (t < 256) sW1[t] = Wl11[t];
  for (int i=t; i<320; i+=256){
    int n = i/20, q = i - n*20;
    *(float4*)&sni[n*84 + q*4] = *(const float4*)(ni + (size_t)(nb+n)*80 + q*4);
  }
  if (t < 16) sna[t] = na[nb + t];
  __syncthreads();
  for (int i=t; i<1280; i+=256){
    int n = i/80, k = i - n*80;
    const float* row = sni + n*84;
    float a = sna[n];
    float acc = 0.f;
    if (k < 32){
      #pragma unroll
      for (int u=0; u<32; ++u) acc += row[u]*sW0[u*32+k];
      y[(size_t)nb*80 + i] = (unsigned short)f2bf(acc * a * 0.17677669529663687f);
    } else {
      int kk = k-32, v = kk/3, ii = kk - v*3;
      #pragma unroll
      for (int u=0; u<16; ++u) acc += row[32+u*3+ii]*sW1[u*16+v];
      y[(size_t)nb*80 + i] = (unsigned short)f2bf(acc * a * 0.25f);
    }
  }
}

// block-level base allocation: per-block prefix scan of 256 counts + ONE
// atomicAdd for the block's base window (order arbitrary, segments contiguous)
__global__ void k_alloc(const int* __restrict__ counts, int* __restrict__ ctr,
                        int* __restrict__ cursor){
  __shared__ int wsum[4];
  __shared__ int s_base;
  const int t = threadIdx.x;
  const int lane = t & 63, wv = t >> 6;
  const int n = blockIdx.x*256 + t;
  int v = (n < N_NODES) ? counts[n] : 0;
  int x = v;
  #pragma unroll
  for (int off=1; off<64; off<<=1){
    int sh = __shfl_up(x, off, 64);
    if (lane >= off) x += sh;
  }
  if (lane == 63) wsum[wv] = x;
  __syncthreads();
  if (t == 0){
    int s0 = wsum[0], s1 = wsum[1], s2 = wsum[2], s3 = wsum[3];
    int total = s0 + s1 + s2 + s3;
    wsum[0] = 0; wsum[1] = s0; wsum[2] = s0+s1; wsum[3] = s0+s1+s2;
    s_base = atomicAdd(ctr, total);
  }
  __syncthreads();
  if (n < N_NODES) cursor[n] = s_base + wsum[wv] + (x - v);
}

// One 32B record per edge at its sorted position (u16 view):
// [0..9]=es bf16, [10..13]=ea bf16, [14..15]=u32 (src<<16|dst)
__global__ void k_fill(const int* __restrict__ ei, const float* __restrict__ ea,
                       const float* __restrict__ es, int* __restrict__ cursor,
                       uint4* __restrict__ meta){
  int e = blockIdx.x*256 + threadIdx.x;
  if (e >= N_EDGES) return;
  int s = ei[e], d = ei[N_EDGES + e];
  int pos = atomicAdd(&cursor[d], 1);
  const float* eap = ea + (size_t)e*4;
  const float* esp = es + (size_t)e*10;
  unsigned int u0 = f2bf(esp[0]) | (f2bf(esp[1])<<16);
  unsigned int u1 = f2bf(esp[2]) | (f2bf(esp[3])<<16);
  unsigned int u2 = f2bf(esp[4]) | (f2bf(esp[5])<<16);
  unsigned int u3 = f2bf(esp[6]) | (f2bf(esp[7])<<16);
  unsigned int u4 = f2bf(esp[8]) | (f2bf(esp[9])<<16);
  unsigned int u5 = f2bf(eap[0]) | (f2bf(eap[1])<<16);
  unsigned int u6 = f2bf(eap[2]) | (f2bf(eap[3])<<16);
  unsigned int u7 = ((unsigned int)s << 16) | (unsigned int)d;
  uint4* mp = meta + (size_t)pos*2;
  mp[0] = make_uint4(u0,u1,u2,u3);
  mp[1] = make_uint4(u4,u5,u6,u7);
}

// ---------------- fused edge MLP + messages + segment-sum ----------------
// bf16 y + bf16 w in LDS => ~31.7 KB/block => 5 blocks/CU by LDS.
// NO waves-per-EU hint (r9/r10: any 2nd launch_bounds arg squeezes VGPRs
// into scratch spills). 32B meta records: lane l holds uint2 = quarter
// (l&3) of edge (l>>2); quarter contents (u16): q0=es0..3, q1=es4..7,
// q2=es8,es9,ea0,ea1, q3=ea2,ea3,(src<<16|dst).
__global__ __launch_bounds__(256) void k_edge(
    const uint2* __restrict__ meta,
    const float* __restrict__ Wfc0, const float* __restrict__ Wfc1,
    const unsigned short* __restrict__ yb, float* __restrict__ agg){
  __shared__ float s_wfc0[640];                    // [k=10][n=64] f32
  __shared__ unsigned short s_w[4][16*98];         // per-wave: [e=16][o=96(+2)] bf16
  __shared__ unsigned short s_y[4][16*88];         // per-wave: y rows bf16, stride 88
  __shared__ float s_m[4][16*20];                  // per-wave: ea[0..3], es[4..13]

  const int t = threadIdx.x;
  const int w = t >> 6, l = t & 63;
  const int r = l & 15, part = l >> 4;
  const int q = l & 3;

  for (int i = t; i < 640; i += 256) s_wfc0[i] = Wfc0[i];

  // B-fragments of Wfc1 (bf16) in registers: lane holds B[k=part*8+j][n=nt*16+r]
  short8 b0[6], b1[6];
  #pragma unroll
  for (int nt=0; nt<6; ++nt){
    #pragma unroll
    for (int j=0; j<8; ++j){
      b0[nt][j] = (short)f2bf(Wfc1[(     part*8+j)*96 + nt*16 + r]);
      b1[nt][j] = (short)f2bf(Wfc1[(32 + part*8+j)*96 + nt*16 + r]);
    }
  }
  __syncthreads();   // only block barrier: s_wfc0 ready

  // per-lane message-channel constants (3 channel passes, c = p*64 + l)
  int o_c[3], yo[3], eai[3];
  #pragma unroll
  for (int p=0; p<3; ++p){
    int c = p*64 + l;
    if (c < 32)      { o_c[p]=c;    yo[p]=c;        eai[p]=0; }
    else if (c < 48) { int u=c-32;  o_c[p]=80+u;    yo[p]=32+3*u; eai[p]=0; }
    else if (c < 144){ int idx=c-48;  int u=idx/3, fi=idx-u*3; o_c[p]=32+u; yo[p]=u;        eai[p]=1+fi; }
    else             { int idx=c-144; int u=idx/3, i =idx-u*3; o_c[p]=64+u; yo[p]=32+3*u+i; eai[p]=0; }
  }
  const bool dot0 = (l >= 32) && (l < 48);

  unsigned short* sw = s_w[w];
  unsigned short* sy = s_y[w];
  float* sm = s_m[w];

  // y-row chunk assignment (16B chunks of the 160B bf16 row)
  const int o0 = (part==0) ? 0 : (part==1) ? 24 : (part==2) ? 40 : 64;
  const bool has3 = (part & 1) == 0;

  const int gw = blockIdx.x*4 + w;
  const int nw = gridDim.x*4;
  const int m0 = (int)(((long long)gw     * N_MT) / nw);
  const int m1 = (int)(((long long)(gw+1) * N_MT) / nw);
  if (m0 >= m1) return;

  // ---- prologue: tile m0 meta (64 uint2 per tile)
  uint2 mreg = meta[(size_t)m0*64 + l];

  float acc0 = 0.f, acc1 = 0.f, acc2 = 0.f;
  int dcur = -1;

  for (int m = m0; m < m1; ++m){
    // ---- next-tile meta prefetch (clamped; only 2 VGPRs cross phases)
    const int mnx = (m+1 < m1) ? (m+1) : m;
    uint2 mnext = meta[(size_t)mnx*64 + l];

    // ---- extract src/dst for this tile (lane 4r+3 holds packed u32 in .y)
    const int packed = __shfl((int)mreg.y, 4*r + 3);
    const int isrc = ((unsigned int)packed) >> 16;
    const int idst = packed & 0xffff;

    // ---- current-tile y gather, bf16 (global->reg->LDS, short live range)
    {
      const unsigned short* yrow = yb + (size_t)isrc*80;
      uint4 va = *(const uint4*)(yrow + o0);
      uint4 vb = *(const uint4*)(yrow + o0 + 8);
      uint4 vc;
      if (has3) vc = *(const uint4*)(yrow + o0 + 16);
      unsigned short* syr = sy + r*88;
      *(uint4*)(syr + o0)      = va;
      *(uint4*)(syr + o0 + 8)  = vb;
      if (has3) *(uint4*)(syr + o0 + 16) = vc;
    }
    // ---- stage meta quarter to s_m (f32 layout: ea[0..3], es[4..13])
    {
      float* sme = sm + (l>>2)*20;
      float f0 = bflo(mreg.x), f1 = bfhi(mreg.x);
      float f2 = bflo(mreg.y), f3 = bfhi(mreg.y);
      if (q == 0){
        sme[4]=f0; sme[5]=f1; sme[6]=f2; sme[7]=f3;        // es0..3
      } else if (q == 1){
        sme[8]=f0; sme[9]=f1; sme[10]=f2; sme[11]=f3;      // es4..7
      } else if (q == 2){
        sme[12]=f0; sme[13]=f1; sme[0]=f2; sme[1]=f3;      // es8,es9,ea0,ea1
      } else {
        sme[2]=f0; sme[3]=f1;                              // ea2,ea3
      }
    }
    wave_lds_fence();

    // ---- layer1: h[r][part*8+j] from s_m es
    const float* esr = sm + r*20 + 4;
    float hv0[8], hv1[8];
    #pragma unroll
    for (int j=0; j<8; ++j){ hv0[j]=0.f; hv1[j]=0.f; }
    #pragma unroll
    for (int k=0; k<10; ++k){
      float ev = esr[k];
      const float* wr = s_wfc0 + k*64 + part*8;
      #pragma unroll
      for (int j=0; j<8; ++j){ hv0[j] += ev*wr[j]; hv1[j] += ev*wr[32+j]; }
    }
    short8 a0, a1;
    #pragma unroll
    for (int j=0; j<8; ++j){
      float x0 = hv0[j]*0.31622776601683794f;   // /sqrt(10)
      float x1 = hv1[j]*0.31622776601683794f;
      a0[j] = (short)f2bf(x0/(1.f+__expf(-x0)));
      a1[j] = (short)f2bf(x1/(1.f+__expf(-x1)));
    }

    // ---- layer2 MFMA: w[e=part*4+rr][o=nt*16+r] -> bf16 LDS
    #pragma unroll
    for (int nt=0; nt<6; ++nt){
      f32x4 acc = {0.f,0.f,0.f,0.f};
      acc = __builtin_amdgcn_mfma_f32_16x16x32_bf16(a0, b0[nt], acc, 0,0,0);
      acc = __builtin_amdgcn_mfma_f32_16x16x32_bf16(a1, b1[nt], acc, 0,0,0);
      #pragma unroll
      for (int rr=0; rr<4; ++rr)
        sw[(part*4+rr)*98 + nt*16 + r] = (unsigned short)f2bf(acc[rr]*0.125f);
    }
    wave_lds_fence();

    // ---- messages + carried segment-sum (3 channels per lane)
    for (int e=0; e<16; ++e){
      int de = __shfl(idst, e);
      if (de != dcur){
        if (dcur >= 0){
          unsafeAtomicAdd(&agg[(size_t)dcur*192 +       l], acc0);
          unsafeAtomicAdd(&agg[(size_t)dcur*192 +  64 + l], acc1);
          unsafeAtomicAdd(&agg[(size_t)dcur*192 + 128 + l], acc2);
        }
        acc0 = acc1 = acc2 = 0.f;
        dcur = de;
      }
      const float* sme = sm + e*20;
      const unsigned short* swe = sw + e*98;
      const unsigned short* sye = sy + e*88;
      float m0v;
      if (dot0){
        m0v = bf2f(swe[o_c[0]]) *
              (bf2f(sye[yo[0]])*sme[1] + bf2f(sye[yo[0]+1])*sme[2] + bf2f(sye[yo[0]+2])*sme[3])
              * 0.5773502691896258f;   // /sqrt(3)
      } else {
        m0v = bf2f(swe[o_c[0]]) * bf2f(sye[yo[0]]) * sme[eai[0]];
      }
      acc0 += m0v;
      acc1 += bf2f(swe[o_c[1]]) * bf2f(sye[yo[1]]) * sme[eai[1]];
      acc2 += bf2f(swe[o_c[2]]) * bf2f(sye[yo[2]]) * sme[eai[2]];
    }
    wave_lds_fence();

    mreg = mnext;
  }
  if (dcur >= 0){
    unsafeAtomicAdd(&agg[(size_t)dcur*192 +       l], acc0);
    unsafeAtomicAdd(&agg[(size_t)dcur*192 +  64 + l], acc1);
    unsafeAtomicAdd(&agg[(size_t)dcur*192 + 128 + l], acc2);
  }
}

// ---------------- finish: z = agg @ W_l2, out = c_s*s + c_x*z ----------------
__global__ void k_finish(const float* __restrict__ ni, const float* __restrict__ na,
    const float* __restrict__ Wsc0, const float* __restrict__ Wsc1,
    const float* __restrict__ Wl20, const float* __restrict__ Wl21,
    const float* __restrict__ agg, float* __restrict__ out){
  __shared__ float sWsc0[1024];   // [32][32]
  __shared__ float sWsc1[256];    // [16][16]
  __shared__ float sWl20[1536];   // [48][32]
  __shared__ float sWl21[768];    // [48][16]
  __shared__ float sni[16*84];    // node rows, stride 84
  __shared__ float sag[16*196];   // agg rows, stride 196
  __shared__ float sna[16];
  const int t = threadIdx.x;
  const int nb = blockIdx.x*16;
  for (int i=t; i<1024; i+=256) sWsc0[i] = Wsc0[i];
  if (t < 256) sWsc1[t] = Wsc1[t];
  for (int i=t; i<1536; i+=256) sWl20[i] = Wl20[i];
  for (int i=t; i<768;  i+=256) sWl21[i] = Wl21[i];
  for (int i=t; i<320;  i+=256){
    int n = i/20, q = i - n*20;
    *(float4*)&sni[n*84 + q*4] = *(const float4*)(ni + (size_t)(nb+n)*80 + q*4);
  }
  for (int i=t; i<768;  i+=256){
    int n = i/48, q = i - n*48;
    *(float4*)&sag[n*196 + q*4] = *(const float4*)(agg + (size_t)(nb+n)*192 + q*4);
  }
  if (t < 16) sna[t] = na[nb + t];
  __syncthreads();

  const float c_s = 0.3826834323650898f;   // sin(pi/8)
  const float c_x = 0.9238795325112867f;   // cos(pi/8)
  const float zscale = 0.17677669529663687f * 0.14433756729740643f; // 1/sqrt(32)/sqrt(48)
  for (int i=t; i<1280; i+=256){
    int n = i/80, k = i - n*80;
    const float* row = sni + n*84;
    const float* ag  = sag + n*196;
    float a = sna[n];
    float s = 0.f, z = 0.f;
    if (k < 32){
      #pragma unroll
      for (int u=0; u<32; ++u) s += row[u]*sWsc0[u*32+k];
      s *= a * 0.17677669529663687f;
      #pragma unroll
      for (int u=0; u<48; ++u) z += ag[u]*sWl20[u*32+k];
    } else {
      int kk=k-32, v=kk/3, ii=kk-v*3;
      #pragma unroll
      for (int u=0; u<16; ++u) s += row[32+u*3+ii]*sWsc1[u*16+v];
      s *= a * 0.25f;
      #pragma unroll
      for (int u=0; u<48; ++u) z += ag[48+u*3+ii]*sWl21[u*16+v];
    }
    out[(size_t)nb*80 + i] = c_s*s + c_x*z*zscale;
  }
}

extern "C" void kernel_launch(void* const* d_in, const int* in_sizes, int n_in,
                              void* d_out, int out_size, void* d_ws, size_t ws_size,
                              hipStream_t stream){
  const float* node_input   = (const float*)d_in[0];
  const float* node_attr    = (const float*)d_in[1];
  const float* edge_attr    = (const float*)d_in[2];
  const float* edge_scalars = (const float*)d_in[3];
  const float* W_sc0 = (const float*)d_in[4];
  const float* W_sc1 = (const float*)d_in[5];
  const float* W_l1_0 = (const float*)d_in[6];
  const float* W_l1_1 = (const float*)d_in[7];
  const float* W_fc0 = (const float*)d_in[8];
  const float* W_fc1 = (const float*)d_in[9];
  const float* W_l2_0 = (const float*)d_in[10];
  const float* W_l2_1 = (const float*)d_in[11];
  const int* edge_index = (const int*)d_in[12];
  float* out = (float*)d_out;

  char* ws = (char*)d_ws;
  unsigned short* y = (unsigned short*)ws;            //  3,200,000 B (bf16)
  float*  agg    = (float*)(ws + 3200000);            // 15,360,000 B
  int*    counts = (int*)(ws + 18560000);             // 80,000 B
  int*    ctr    = (int*)(ws + 18640000);             // 64 B
  int*    cursor = (int*)(ws + 18640064);             // 80,000 B
  uint4*  meta   = (uint4*)(ws + 18722048);           // 20,480,000 B (64-aligned)

  // zero counts + ctr (agg zeroed inside k_pre)
  hipMemsetAsync(counts, 0, 80064, stream);

  k_pre  <<<HIST_BLOCKS + YN_BLOCKS + AGGZ_BLOCKS, 256, 0, stream>>>(
            edge_index, counts, node_input, node_attr, W_l1_0, W_l1_1,
            y, (float4*)agg);
  k_alloc<<<(N_NODES+255)/256, 256, 0, stream>>>(counts, ctr, cursor);
  k_fill <<<(N_EDGES+255)/256, 256, 0, stream>>>(edge_index, edge_attr, edge_scalars,
                                                 cursor, meta);
  k_edge <<<1280, 256, 0, stream>>>((const uint2*)meta, W_fc0, W_fc1, y, agg);
  k_finish<<<YN_BLOCKS, 256, 0, stream>>>(node_input, node_attr, W_sc0, W_sc1,
                                          W_l2_0, W_l2_1, agg, out);
}

// Round 13
// 322.291 us; speedup vs baseline: 1.2057x; 1.0468x over previous
//
#include <hip/hip_runtime.h>

#define N_NODES 20000
#define N_EDGES 640000
#define N_MT (N_EDGES/16)   // 40000 microtiles of 16 edges

typedef short short8 __attribute__((ext_vector_type(8)));
typedef float f32x4 __attribute__((ext_vector_type(4)));

// RNE float -> bf16 bits
__device__ __forceinline__ unsigned int f2bf(float x){
  unsigned int u = __builtin_bit_cast(unsigned int, x);
  u += 0x7fffu + ((u >> 16) & 1u);
  return u >> 16;
}
__device__ __forceinline__ float bf2f(unsigned short u){
  unsigned int v = ((unsigned int)u) << 16;
  return __builtin_bit_cast(float, v);
}

__device__ __forceinline__ void wave_lds_fence(){
  __asm__ volatile("s_waitcnt lgkmcnt(0)" ::: "memory");
}
__device__ __forceinline__ void wave_vm_fence(){
  __asm__ volatile("s_waitcnt vmcnt(0)" ::: "memory");
}

// async global->LDS, 16B per lane; LDS dest = uniform base + laneId*16
__device__ __forceinline__ void gload16(const void* g, void* l){
  __builtin_amdgcn_global_load_lds(
      (const __attribute__((address_space(1))) unsigned int*)g,
      (__attribute__((address_space(3))) unsigned int*)l,
      16, 0, 0);
}

#define HIST_BLOCKS 625                    // 4 edges/thread, int4 loads
#define YN_BLOCKS   (N_NODES/16)           // 1250 (16 nodes per block)
#define AGGZ_BLOCKS 938                    // zero 3,840,000 floats, 16/thread

// ---- fused: edge-dst histogram + y = l1 linear (bf16 out) + agg zeroing ----
__global__ void k_pre(const int* __restrict__ ei, int* __restrict__ counts,
                      const float* __restrict__ ni, const float* __restrict__ na,
                      const float* __restrict__ Wl10, const float* __restrict__ Wl11,
                      unsigned short* __restrict__ y, float4* __restrict__ aggz){
  if (blockIdx.x < HIST_BLOCKS){
    int i = blockIdx.x*256 + threadIdx.x;
    if (i < N_EDGES/4){
      int4 d4 = *(const int4*)(ei + N_EDGES + i*4);
      atomicAdd(&counts[d4.x], 1);
      atomicAdd(&counts[d4.y], 1);
      atomicAdd(&counts[d4.z], 1);
      atomicAdd(&counts[d4.w], 1);
    }
    return;
  }
  if (blockIdx.x >= HIST_BLOCKS + YN_BLOCKS){
    int i = (blockIdx.x - HIST_BLOCKS - YN_BLOCKS)*256 + threadIdx.x;
    if (i < 240000){
      float4 z = {0.f,0.f,0.f,0.f};
      float4* p = aggz + (size_t)i*4;
      p[0]=z; p[1]=z; p[2]=z; p[3]=z;
    }
    return;
  }
  __shared__ float sW0[1024];
  __shared__ float sW1[256];
  __shared__ float sni[16*84];
  __shared__ float sna[16];
  const int t = threadIdx.x;
  const int nb = (blockIdx.x - HIST_BLOCKS)*16;
  for (int i=t; i<1024; i+=256) sW0[i] = Wl10[i];
  if (t < 256) sW1[t] = Wl11[t];
  for (int i=t; i<320; i+=256){
    int n = i/20, q = i - n*20;
    *(float4*)&sni[n*84 + q*4] = *(const float4*)(ni + (size_t)(nb+n)*80 + q*4);
  }
  if (t < 16) sna[t] = na[nb + t];
  __syncthreads();
  for (int i=t; i<1280; i+=256){
    int n = i/80, k = i - n*80;
    const float* row = sni + n*84;
    float a = sna[n];
    float acc = 0.f;
    if (k < 32){
      #pragma unroll
      for (int u=0; u<32; ++u) acc += row[u]*sW0[u*32+k];
      y[(size_t)nb*80 + i] = (unsigned short)f2bf(acc * a * 0.17677669529663687f);
    } else {
      int kk = k-32, v = kk/3, ii = kk - v*3;
      #pragma unroll
      for (int u=0; u<16; ++u) acc += row[32+u*3+ii]*sW1[u*16+v];
      y[(size_t)nb*80 + i] = (unsigned short)f2bf(acc * a * 0.25f);
    }
  }
}

// block-level base allocation (one atomic per 256 nodes)
__global__ void k_alloc(const int* __restrict__ counts, int* __restrict__ ctr,
                        int* __restrict__ cursor){
  __shared__ int wsum[4];
  __shared__ int s_base;
  const int t = threadIdx.x;
  const int lane = t & 63, wv = t >> 6;
  const int n = blockIdx.x*256 + t;
  int v = (n < N_NODES) ? counts[n] : 0;
  int x = v;
  #pragma unroll
  for (int off=1; off<64; off<<=1){
    int sh = __shfl_up(x, off, 64);
    if (lane >= off) x += sh;
  }
  if (lane == 63) wsum[wv] = x;
  __syncthreads();
  if (t == 0){
    int s0 = wsum[0], s1 = wsum[1], s2 = wsum[2], s3 = wsum[3];
    int total = s0 + s1 + s2 + s3;
    wsum[0] = 0; wsum[1] = s0; wsum[2] = s0+s1; wsum[3] = s0+s1+s2;
    s_base = atomicAdd(ctr, total);
  }
  __syncthreads();
  if (n < N_NODES) cursor[n] = s_base + wsum[wv] + (x - v);
}

// One 32B record per edge at its sorted position (u16 view):
// [0..9]=es bf16, [10..13]=ea bf16, [14..15]=u32 (src<<16|dst)
__global__ void k_fill(const int* __restrict__ ei, const float* __restrict__ ea,
                       const float* __restrict__ es, int* __restrict__ cursor,
                       uint4* __restrict__ meta){
  int e = blockIdx.x*256 + threadIdx.x;
  if (e >= N_EDGES) return;
  int s = ei[e], d = ei[N_EDGES + e];
  int pos = atomicAdd(&cursor[d], 1);
  const float* eap = ea + (size_t)e*4;
  const float* esp = es + (size_t)e*10;
  unsigned int u0 = f2bf(esp[0]) | (f2bf(esp[1])<<16);
  unsigned int u1 = f2bf(esp[2]) | (f2bf(esp[3])<<16);
  unsigned int u2 = f2bf(esp[4]) | (f2bf(esp[5])<<16);
  unsigned int u3 = f2bf(esp[6]) | (f2bf(esp[7])<<16);
  unsigned int u4 = f2bf(esp[8]) | (f2bf(esp[9])<<16);
  unsigned int u5 = f2bf(eap[0]) | (f2bf(eap[1])<<16);
  unsigned int u6 = f2bf(eap[2]) | (f2bf(eap[3])<<16);
  unsigned int u7 = ((unsigned int)s << 16) | (unsigned int)d;
  uint4* mp = meta + (size_t)pos*2;
  mp[0] = make_uint4(u0,u1,u2,u3);
  mp[1] = make_uint4(u4,u5,u6,u7);
}

// ---------------- fused edge MLP + messages + segment-sum ----------------
// Per-wave double-buffered pipeline: tile m+1's y rows are DMA'd straight
// into LDS (global_load_lds, no VGPR round-trip) and its meta staged raw,
// both during tile m's compute. vmcnt(0) at loop top waits on loads that
// had a full tile (~800 cyc) to complete. 43.8 KB LDS => 3 blocks/CU.
// NO waves-per-EU hint (r9/r10: it forces VGPR squeeze -> scratch spills).
__global__ __launch_bounds__(256) void k_edge(
    const uint2* __restrict__ meta,
    const float* __restrict__ Wfc0, const float* __restrict__ Wfc1,
    const unsigned short* __restrict__ yb, float* __restrict__ agg){
  __shared__ float s_wfc0[640];                            // [k=10][n=64] f32
  __shared__ __align__(16) unsigned short s_w[4][16*98];   // per-wave [e][o] bf16
  __shared__ __align__(16) unsigned short s_y[4][2][16*96];// dbuf y rows, stride 96 u16 (192B=12 chunks)
  __shared__ __align__(16) unsigned int  s_m[4][2][16*8];  // dbuf raw 32B records

  const int t = threadIdx.x;
  const int w = t >> 6, l = t & 63;
  const int r = l & 15, part = l >> 4;

  for (int i = t; i < 640; i += 256) s_wfc0[i] = Wfc0[i];

  // B-fragments of Wfc1 (bf16) in registers
  short8 b0[6], b1[6];
  #pragma unroll
  for (int nt=0; nt<6; ++nt){
    #pragma unroll
    for (int j=0; j<8; ++j){
      b0[nt][j] = (short)f2bf(Wfc1[(     part*8+j)*96 + nt*16 + r]);
      b1[nt][j] = (short)f2bf(Wfc1[(32 + part*8+j)*96 + nt*16 + r]);
    }
  }
  __syncthreads();   // only block barrier: s_wfc0 ready

  // per-lane message-channel constants
  int o_c[3], yo[3], eai[3];
  #pragma unroll
  for (int p=0; p<3; ++p){
    int c = p*64 + l;
    if (c < 32)      { o_c[p]=c;    yo[p]=c;        eai[p]=0; }
    else if (c < 48) { int u=c-32;  o_c[p]=80+u;    yo[p]=32+3*u; eai[p]=0; }
    else if (c < 144){ int idx=c-48;  int u=idx/3, fi=idx-u*3; o_c[p]=32+u; yo[p]=u;        eai[p]=1+fi; }
    else             { int idx=c-144; int u=idx/3, i =idx-u*3; o_c[p]=64+u; yo[p]=32+3*u+i; eai[p]=0; }
  }
  const bool dot0 = (l >= 32) && (l < 48);

  unsigned short* sw = s_w[w];

  // y chunk assignment: instr i, lane l -> chunk idx=i*64+l; row=idx/12,
  // chunk-in-row byte offset = (idx%12)*16 (rows padded 160B->192B)
  int row_i[3], cir_i[3];
  #pragma unroll
  for (int i=0; i<3; ++i){
    int idx = i*64 + l;
    row_i[i] = idx/12;
    cir_i[i] = (idx - 12*row_i[i])*16;
  }

  const int gw = blockIdx.x*4 + w;
  const int nw = gridDim.x*4;
  const int m0 = (int)(((long long)gw     * N_MT) / nw);
  const int m1 = (int)(((long long)(gw+1) * N_MT) / nw);
  if (m0 >= m1) return;

  // ---- prologue: stage tile m0 into buffer 0
  uint2 mreg = meta[(size_t)m0*64 + l];
  {
    unsigned short* syn = s_y[w][0];
    #pragma unroll
    for (int i=0; i<3; ++i){
      int pk = __shfl((int)mreg.y, 4*row_i[i] + 3);
      unsigned src = ((unsigned)pk) >> 16;
      gload16((const char*)yb + (size_t)src*160 + cir_i[i], (char*)syn + i*1024);
    }
    *(uint2*)(&s_m[w][0][(l>>2)*8 + (l&3)*2]) = mreg;
  }
  mreg = meta[(size_t)((m0+1 < m1) ? m0+1 : m1-1)*64 + l];

  float acc0 = 0.f, acc1 = 0.f, acc2 = 0.f;
  int dcur = -1;
  int b = 0;

  for (int m = m0; m < m1; ++m){
    // ---- y(m) landed in s_y[b]; mreg = meta(m+1) ready
    wave_vm_fence();
    const int nb2 = b ^ 1;
    // ---- issue tile m+1 staging (DMA y -> s_y[nb2], raw meta -> s_m[nb2])
    {
      unsigned short* syn = s_y[w][nb2];
      #pragma unroll
      for (int i=0; i<3; ++i){
        int pk = __shfl((int)mreg.y, 4*row_i[i] + 3);
        unsigned src = ((unsigned)pk) >> 16;
        gload16((const char*)yb + (size_t)src*160 + cir_i[i], (char*)syn + i*1024);
      }
      *(uint2*)(&s_m[w][nb2][(l>>2)*8 + (l&3)*2]) = mreg;
    }
    // ---- prefetch meta(m+2)
    {
      int mnx = (m+2 < m1) ? m+2 : m1-1;
      mreg = meta[(size_t)mnx*64 + l];
    }
    wave_lds_fence();   // s_m writes visible (covers prologue on first iter)

    const unsigned int* smu = s_m[w][b];
    const unsigned short* syb = s_y[w][b];

    // ---- layer1: h[r][part*8+j] from raw record es (bf16)
    const unsigned short* esr = (const unsigned short*)(smu + r*8);
    float hv0[8], hv1[8];
    #pragma unroll
    for (int j=0; j<8; ++j){ hv0[j]=0.f; hv1[j]=0.f; }
    #pragma unroll
    for (int k=0; k<10; ++k){
      float ev = bf2f(esr[k]);
      const float* wr = s_wfc0 + k*64 + part*8;
      #pragma unroll
      for (int j=0; j<8; ++j){ hv0[j] += ev*wr[j]; hv1[j] += ev*wr[32+j]; }
    }
    short8 a0, a1;
    #pragma unroll
    for (int j=0; j<8; ++j){
      float x0 = hv0[j]*0.31622776601683794f;   // /sqrt(10)
      float x1 = hv1[j]*0.31622776601683794f;
      a0[j] = (short)f2bf(x0/(1.f+__expf(-x0)));
      a1[j] = (short)f2bf(x1/(1.f+__expf(-x1)));
    }

    // ---- layer2 MFMA: w[e=part*4+rr][o=nt*16+r] -> bf16 LDS
    #pragma unroll
    for (int nt=0; nt<6; ++nt){
      f32x4 acc = {0.f,0.f,0.f,0.f};
      acc = __builtin_amdgcn_mfma_f32_16x16x32_bf16(a0, b0[nt], acc, 0,0,0);
      acc = __builtin_amdgcn_mfma_f32_16x16x32_bf16(a1, b1[nt], acc, 0,0,0);
      #pragma unroll
      for (int rr=0; rr<4; ++rr)
        sw[(part*4+rr)*98 + nt*16 + r] = (unsigned short)f2bf(acc[rr]*0.125f);
    }
    wave_lds_fence();   // s_w visible

    // ---- messages + carried segment-sum (3 channels per lane)
    for (int e=0; e<16; ++e){
      int de = (int)(smu[e*8 + 7] & 0xffffu);   // broadcast LDS read
      if (de != dcur){
        if (dcur >= 0){
          unsafeAtomicAdd(&agg[(size_t)dcur*192 +       l], acc0);
          unsafeAtomicAdd(&agg[(size_t)dcur*192 +  64 + l], acc1);
          unsafeAtomicAdd(&agg[(size_t)dcur*192 + 128 + l], acc2);
        }
        acc0 = acc1 = acc2 = 0.f;
        dcur = de;
      }
      const unsigned short* sme = (const unsigned short*)(smu + e*8);
      const unsigned short* swe = sw + e*98;
      const unsigned short* sye = syb + e*96;
      float m0v;
      if (dot0){
        m0v = bf2f(swe[o_c[0]]) *
              (bf2f(sye[yo[0]])*bf2f(sme[11]) + bf2f(sye[yo[0]+1])*bf2f(sme[12])
               + bf2f(sye[yo[0]+2])*bf2f(sme[13]))
              * 0.5773502691896258f;   // /sqrt(3)
      } else {
        m0v = bf2f(swe[o_c[0]]) * bf2f(sye[yo[0]]) * bf2f(sme[10 + eai[0]]);
      }
      acc0 += m0v;
      acc1 += bf2f(swe[o_c[1]]) * bf2f(sye[yo[1]]) * bf2f(sme[10 + eai[1]]);
      acc2 += bf2f(swe[o_c[2]]) * bf2f(sye[yo[2]]) * bf2f(sme[10 + eai[2]]);
    }

    b = nb2;
  }
  if (dcur >= 0){
    unsafeAtomicAdd(&agg[(size_t)dcur*192 +       l], acc0);
    unsafeAtomicAdd(&agg[(size_t)dcur*192 +  64 + l], acc1);
    unsafeAtomicAdd(&agg[(size_t)dcur*192 + 128 + l], acc2);
  }
}

// ---------------- finish: z = agg @ W_l2, out = c_s*s + c_x*z ----------------
__global__ void k_finish(const float* __restrict__ ni, const float* __restrict__ na,
    const float* __restrict__ Wsc0, const float* __restrict__ Wsc1,
    const float* __restrict__ Wl20, const float* __restrict__ Wl21,
    const float* __restrict__ agg, float* __restrict__ out){
  __shared__ float sWsc0[1024];
  __shared__ float sWsc1[256];
  __shared__ float sWl20[1536];
  __shared__ float sWl21[768];
  __shared__ float sni[16*84];
  __shared__ float sag[16*196];
  __shared__ float sna[16];
  const int t = threadIdx.x;
  const int nb = blockIdx.x*16;
  for (int i=t; i<1024; i+=256) sWsc0[i] = Wsc0[i];
  if (t < 256) sWsc1[t] = Wsc1[t];
  for (int i=t; i<1536; i+=256) sWl20[i] = Wl20[i];
  for (int i=t; i<768;  i+=256) sWl21[i] = Wl21[i];
  for (int i=t; i<320;  i+=256){
    int n = i/20, q = i - n*20;
    *(float4*)&sni[n*84 + q*4] = *(const float4*)(ni + (size_t)(nb+n)*80 + q*4);
  }
  for (int i=t; i<768;  i+=256){
    int n = i/48, q = i - n*48;
    *(float4*)&sag[n*196 + q*4] = *(const float4*)(agg + (size_t)(nb+n)*192 + q*4);
  }
  if (t < 16) sna[t] = na[nb + t];
  __syncthreads();

  const float c_s = 0.3826834323650898f;   // sin(pi/8)
  const float c_x = 0.9238795325112867f;   // cos(pi/8)
  const float zscale = 0.17677669529663687f * 0.14433756729740643f;
  for (int i=t; i<1280; i+=256){
    int n = i/80, k = i - n*80;
    const float* row = sni + n*84;
    const float* ag  = sag + n*196;
    float a = sna[n];
    float s = 0.f, z = 0.f;
    if (k < 32){
      #pragma unroll
      for (int u=0; u<32; ++u) s += row[u]*sWsc0[u*32+k];
      s *= a * 0.17677669529663687f;
      #pragma unroll
      for (int u=0; u<48; ++u) z += ag[u]*sWl20[u*32+k];
    } else {
      int kk=k-32, v=kk/3, ii=kk-v*3;
      #pragma unroll
      for (int u=0; u<16; ++u) s += row[32+u*3+ii]*sWsc1[u*16+v];
      s *= a * 0.25f;
      #pragma unroll
      for (int u=0; u<48; ++u) z += ag[48+u*3+ii]*sWl21[u*16+v];
    }
    out[(size_t)nb*80 + i] = c_s*s + c_x*z*zscale;
  }
}

extern "C" void kernel_launch(void* const* d_in, const int* in_sizes, int n_in,
                              void* d_out, int out_size, void* d_ws, size_t ws_size,
                              hipStream_t stream){
  const float* node_input   = (const float*)d_in[0];
  const float* node_attr    = (const float*)d_in[1];
  const float* edge_attr    = (const float*)d_in[2];
  const float* edge_scalars = (const float*)d_in[3];
  const float* W_sc0 = (const float*)d_in[4];
  const float* W_sc1 = (const float*)d_in[5];
  const float* W_l1_0 = (const float*)d_in[6];
  const float* W_l1_1 = (const float*)d_in[7];
  const float* W_fc0 = (const float*)d_in[8];
  const float* W_fc1 = (const float*)d_in[9];
  const float* W_l2_0 = (const float*)d_in[10];
  const float* W_l2_1 = (const float*)d_in[11];
  const int* edge_index = (const int*)d_in[12];
  float* out = (float*)d_out;

  char* ws = (char*)d_ws;
  unsigned short* y = (unsigned short*)ws;            //  3,200,000 B (bf16)
  float*  agg    = (float*)(ws + 3200000);            // 15,360,000 B
  int*    counts = (int*)(ws + 18560000);             // 80,000 B
  int*    ctr    = (int*)(ws + 18640000);             // 64 B
  int*    cursor = (int*)(ws + 18640064);             // 80,000 B
  uint4*  meta   = (uint4*)(ws + 18722048);           // 20,480,000 B (64-aligned)

  // zero counts + ctr (agg zeroed inside k_pre)
  hipMemsetAsync(counts, 0, 80064, stream);

  k_pre  <<<HIST_BLOCKS + YN_BLOCKS + AGGZ_BLOCKS, 256, 0, stream>>>(
            edge_index, counts, node_input, node_attr, W_l1_0, W_l1_1,
            y, (float4*)agg);
  k_alloc<<<(N_NODES+255)/256, 256, 0, stream>>>(counts, ctr, cursor);
  k_fill <<<(N_EDGES+255)/256, 256, 0, stream>>>(edge_index, edge_attr, edge_scalars,
                                                 cursor, meta);
  k_edge <<<768, 256, 0, stream>>>((const uint2*)meta, W_fc0, W_fc1, y, agg);
  k_finish<<<YN_BLOCKS, 256, 0, stream>>>(node_input, node_attr, W_sc0, W_sc1,
                                          W_l2_0, W_l2_1, agg, out);
}